// Round 1
// baseline (931.522 us; speedup 1.0000x reference)
//
#include <hip/hip_runtime.h>
#include <hip/hip_bf16.h>
#include <cmath>

#define TT 512
#define BB 32
#define EE 256
#define HH 128
#define KCRF 12
#define NEGF (-10000.0f)

// ---------------------------------------------------------------------------
// K1: XG[row=t*32+b][col 0..1023] = embed[sent[b,t]] . W_cat[col]^T + bias
//     col<512 -> forward gates, col>=512 -> reverse gates
// fp32 tiled GEMM: tile 64 rows x 128 cols, K-chunk 32. 256 threads, 4x8 micro.
// ---------------------------------------------------------------------------
__global__ __launch_bounds__(256) void k1_xg(const int* __restrict__ sent,
    const float* __restrict__ embed,
    const float* __restrict__ Wf, const float* __restrict__ bf,
    const float* __restrict__ Wr, const float* __restrict__ br,
    float* __restrict__ XG)
{
  __shared__ __align__(16) float As[64][36];
  __shared__ __align__(16) float Bs[128][36];
  const int tid = threadIdx.x;
  const int m0 = (blockIdx.x >> 3) * 64;
  const int n0 = (blockIdx.x & 7) * 128;
  const int ty = tid >> 4, tx = tid & 15;
  float acc[4][8];
#pragma unroll
  for (int i = 0; i < 4; ++i)
#pragma unroll
    for (int j = 0; j < 8; ++j) acc[i][j] = 0.f;

  for (int k0 = 0; k0 < 256; k0 += 32) {
#pragma unroll
    for (int r = 0; r < 2; ++r) {           // A: 64x32 gathered embed rows
      int idx = tid + r * 256;
      int row = idx >> 3;
      int c4 = (idx & 7) << 2;
      int R = m0 + row;
      int t = R >> 5, b = R & 31;
      const float4 v = *(const float4*)(embed + (long)sent[b * TT + t] * 256 + k0 + c4);
      *(float4*)&As[row][c4] = v;
    }
#pragma unroll
    for (int r = 0; r < 4; ++r) {           // B: 128x32 of W_cat
      int idx = tid + r * 256;
      int row = idx >> 3;
      int c4 = (idx & 7) << 2;
      int col = n0 + row;
      const float* src = (col < 512) ? (Wf + (long)col * 256) : (Wr + (long)(col - 512) * 256);
      const float4 v = *(const float4*)(src + k0 + c4);
      *(float4*)&Bs[row][c4] = v;
    }
    __syncthreads();
#pragma unroll
    for (int kk = 0; kk < 32; ++kk) {
      float a[4], bv[8];
#pragma unroll
      for (int i = 0; i < 4; ++i) a[i] = As[ty * 4 + i][kk];
#pragma unroll
      for (int j = 0; j < 8; ++j) bv[j] = Bs[tx + 16 * j][kk];
#pragma unroll
      for (int i = 0; i < 4; ++i)
#pragma unroll
        for (int j = 0; j < 8; ++j) acc[i][j] = fmaf(a[i], bv[j], acc[i][j]);
    }
    __syncthreads();
  }
#pragma unroll
  for (int i = 0; i < 4; ++i) {
    int R = m0 + ty * 4 + i;
#pragma unroll
    for (int j = 0; j < 8; ++j) {
      int col = n0 + tx + 16 * j;
      float bias = (col < 512) ? bf[col] : br[col - 512];
      XG[(long)R * 1024 + col] = acc[i][j] + bias;
    }
  }
}

// ---------------------------------------------------------------------------
// K2: LSTM scans. One workgroup per (dir, batch) chain -> 64 WGs, no cross-WG
// sync. 512 threads: thread j owns gate column j; W_hh row in 128 VGPRs,
// h broadcast via LDS, xg prefetched one step ahead.
// HS[row=t*32+b][0..127]=fwd h, [128..255]=rev h (original time order).
// ---------------------------------------------------------------------------
__global__ __launch_bounds__(512) void k2_scan(const float* __restrict__ XG,
    const float* __restrict__ Whf, const float* __restrict__ Whr,
    const float* __restrict__ h0, const float* __restrict__ c0,
    float* __restrict__ HS)
{
  const int wg = blockIdx.x;
  const int dir = wg >> 5;
  const int b = wg & 31;
  const int j = threadIdx.x;
  const float* Wh = dir ? Whr : Whf;

  float w[128];
#pragma unroll
  for (int i = 0; i < 32; ++i) {
    float4 v = *(const float4*)(Wh + (long)j * 128 + i * 4);
    w[4 * i + 0] = v.x; w[4 * i + 1] = v.y; w[4 * i + 2] = v.z; w[4 * i + 3] = v.w;
  }

  __shared__ __align__(16) float hs[128];
  __shared__ float gs[512];
  float c = 0.f;
  if (j < 128) {
    hs[j] = h0[(dir * 32 + b) * 128 + j];
    c = c0[(dir * 32 + b) * 128 + j];
  }
  __syncthreads();

  const int t0 = dir ? (TT - 1) : 0;
  float xg_cur = XG[((long)t0 * 32 + b) * 1024 + dir * 512 + j];
  const int gate = j >> 7;   // 0=i 1=f 2=g 3=o

  for (int s = 0; s < TT; ++s) {
    const int t = dir ? (TT - 1 - s) : s;
    float xg_nxt = 0.f;
    if (s + 1 < TT) {
      int tn = dir ? (TT - 2 - s) : (s + 1);
      xg_nxt = XG[((long)tn * 32 + b) * 1024 + dir * 512 + j];
    }
    float acc = xg_cur;
#pragma unroll
    for (int i = 0; i < 32; ++i) {
      float4 hv = *(const float4*)(hs + 4 * i);   // broadcast read
      acc = fmaf(w[4 * i + 0], hv.x, acc);
      acc = fmaf(w[4 * i + 1], hv.y, acc);
      acc = fmaf(w[4 * i + 2], hv.z, acc);
      acc = fmaf(w[4 * i + 3], hv.w, acc);
    }
    float act = (gate == 2) ? tanhf(acc) : (1.f / (1.f + expf(-acc)));
    gs[j] = act;
    __syncthreads();
    if (j < 128) {
      float ig = gs[j], fg = gs[128 + j], gg = gs[256 + j], og = gs[384 + j];
      c = fmaf(fg, c, ig * gg);
      float h = og * tanhf(c);
      hs[j] = h;
      HS[((long)t * 32 + b) * 256 + dir * 128 + j] = h;
    }
    __syncthreads();
    xg_cur = xg_nxt;
  }
}

// ---------------------------------------------------------------------------
// K3: feats. FE layout [t][k][b] so K4's per-step loads coalesce.
// 256 WGs x 64 threads; one row (t,b) per thread; W_out broadcast from LDS.
// ---------------------------------------------------------------------------
__global__ __launch_bounds__(64) void k3_feats(const float* __restrict__ HS,
    const float* __restrict__ Wout, const float* __restrict__ bout,
    float* __restrict__ FE)
{
  __shared__ __align__(16) float ws[12 * 256];
  __shared__ float bs[12];
  const int tid = threadIdx.x;
  for (int i = tid; i < 768; i += 64)
    ((float4*)ws)[i] = ((const float4*)Wout)[i];
  if (tid < 12) bs[tid] = bout[tid];
  __syncthreads();
  const long row = (long)blockIdx.x * 64 + tid;
  const float4* hp = (const float4*)(HS + row * 256);
  float acc[12];
#pragma unroll
  for (int k = 0; k < 12; ++k) acc[k] = bs[k];
  for (int e4 = 0; e4 < 64; ++e4) {
    float4 hv = hp[e4];
#pragma unroll
    for (int k = 0; k < 12; ++k) {
      const float4 wv = *(const float4*)&ws[k * 256 + e4 * 4];
      acc[k] = fmaf(hv.x, wv.x, acc[k]);
      acc[k] = fmaf(hv.y, wv.y, acc[k]);
      acc[k] = fmaf(hv.z, wv.z, acc[k]);
      acc[k] = fmaf(hv.w, wv.w, acc[k]);
    }
  }
  const int t = (int)(row >> 5), b = (int)(row & 31);
#pragma unroll
  for (int k = 0; k < 12; ++k) FE[((long)t * 12 + k) * 32 + b] = acc[k];
}

// ---------------------------------------------------------------------------
// K4: Viterbi forward scan (384 threads = next*32+b) + 32-lane backtrace.
// Strict > keeps first max index == jnp.argmax semantics.
// ---------------------------------------------------------------------------
__global__ __launch_bounds__(384) void k4_viterbi(const float* __restrict__ FE,
    const float* __restrict__ trans, unsigned char* __restrict__ PTR,
    int* __restrict__ out)
{
  __shared__ float sc[32][13];
  __shared__ float tr[144];
  __shared__ int btag[32];
  const int tid = threadIdx.x;
  const int b = tid & 31, nxt = tid >> 5;
  if (tid < 144) tr[tid] = trans[tid];
  if (nxt == 0) {
#pragma unroll
    for (int p = 0; p < 12; ++p) sc[b][p] = (p == 9) ? 0.f : NEGF;  // START=9
  }
  __syncthreads();
  float fnext = FE[nxt * 32 + b];
  for (int t = 0; t < TT; ++t) {
    const float feat = fnext;
    if (t + 1 < TT) fnext = FE[(t + 1) * 384 + nxt * 32 + b];
    float best = -1e30f; int arg = 0;
#pragma unroll
    for (int p = 0; p < 12; ++p) {
      float v = sc[b][p] + tr[nxt * 12 + p];
      if (v > best) { best = v; arg = p; }
    }
    __syncthreads();           // all reads of sc done
    sc[b][nxt] = best + feat;
    PTR[(t * 32 + b) * 12 + nxt] = (unsigned char)arg;
    __syncthreads();
  }
  if (nxt == 0) {              // final scores + trans[STOP=10]
    float best = -1e30f; int arg = 0;
#pragma unroll
    for (int p = 0; p < 12; ++p) {
      float v = sc[b][p] + tr[10 * 12 + p];
      if (v > best) { best = v; arg = p; }
    }
    btag[b] = arg;
  }
  __syncthreads();
  if (tid < 32) {
    int tag = btag[b];
    for (int t = TT - 1; t >= 0; --t) {
      out[b * TT + t] = tag;
      if (t > 0) tag = PTR[(t * 32 + b) * 12 + tag];
    }
  }
}

// ---------------------------------------------------------------------------
extern "C" void kernel_launch(void* const* d_in, const int* in_sizes, int n_in,
                              void* d_out, int out_size, void* d_ws, size_t ws_size,
                              hipStream_t stream)
{
  const int* sent = (const int*)d_in[0];
  const float* h0 = (const float*)d_in[1];
  const float* c0 = (const float*)d_in[2];
  const float* embed = (const float*)d_in[3];
  const float* Wif = (const float*)d_in[4];
  const float* Whf = (const float*)d_in[5];
  const float* bf = (const float*)d_in[6];
  const float* Wir = (const float*)d_in[7];
  const float* Whr = (const float*)d_in[8];
  const float* br = (const float*)d_in[9];
  const float* Wout = (const float*)d_in[10];
  const float* bout = (const float*)d_in[11];
  const float* trans = (const float*)d_in[12];

  char* ws = (char*)d_ws;
  float* XG = (float*)ws;                                   // 16384*1024*4 = 67,108,864 B
  float* HS = (float*)(ws + 67108864);                      // 16384*256*4  = 16,777,216 B
  float* FE = (float*)(ws + 67108864 + 16777216);           // 512*12*32*4  =    786,432 B
  unsigned char* PTR = (unsigned char*)(ws + 67108864 + 16777216 + 786432); // 196,608 B
  int* out = (int*)d_out;

  hipLaunchKernelGGL(k1_xg, dim3(2048), dim3(256), 0, stream,
                     sent, embed, Wif, bf, Wir, br, XG);
  hipLaunchKernelGGL(k2_scan, dim3(64), dim3(512), 0, stream,
                     XG, Whf, Whr, h0, c0, HS);
  hipLaunchKernelGGL(k3_feats, dim3(256), dim3(64), 0, stream,
                     HS, Wout, bout, FE);
  hipLaunchKernelGGL(k4_viterbi, dim3(1), dim3(384), 0, stream,
                     FE, trans, PTR, out);
}